// Round 1
// baseline (524.459 us; speedup 1.0000x reference)
//
#include <hip/hip_runtime.h>

#define NT  256   // threads per block (4 waves)
#define SPB 32    // samples per block

__global__ __launch_bounds__(NT, 3)
void lila_fused(const float* __restrict__ inp,
                const float* __restrict__ W1, const float* __restrict__ b1,
                const float* __restrict__ W2, const float* __restrict__ b2,
                const float* __restrict__ W3, const float* __restrict__ b3,
                const float* __restrict__ V1, const float* __restrict__ c1,
                const float* __restrict__ V2, const float* __restrict__ c2,
                const float* __restrict__ V3, const float* __restrict__ c3,
                float* __restrict__ out)
{
    // LDS: 18560 + 4096 + 18944 + 4224 = 45824 B  -> 3 blocks/CU
    __shared__ __align__(16) float lv1[145 * 32];
    __shared__ __align__(16) float lw2[32 * 32];
    __shared__ __align__(16) float lsight[SPB * 148]; // stride 148: 16B-aligned rows, banks spread
    __shared__ __align__(16) float le1[SPB * 33];     // stride 33: breaks 8-way bank collision

    const int tid = threadIdx.x;
    const int s0  = blockIdx.x * SPB;

    // ---- stage V1, V2 into LDS (consumed after the phase-1 barrier) ----
    {
        const float4* v1g = (const float4*)V1;
        float4*       v1l = (float4*)lv1;
        #pragma unroll
        for (int i = 0; i < (145 * 32) / (4 * NT) + 1; ++i) {
            int idx = tid + i * NT;
            if (idx < (145 * 32) / 4) v1l[idx] = v1g[idx];
        }
        ((float4*)lw2)[tid] = ((const float4*)V2)[tid]; // 1024/4 == NT exactly
    }

    // ---- phase 1: (sample, window) tasks: 54 -> 12 -> 12 -> 4 ----
    for (int t = tid; t < SPB * 36; t += NT) {
        const int s = t / 36;
        const int w = t - s * 36;
        const int x = w / 6;
        const int y = w - x * 6;
        const float* base = inp + (size_t)(s0 + s) * 385 + x * 48 + y * 6;

        float win[54];
        #pragma unroll
        for (int ox = 0; ox < 3; ++ox)
            #pragma unroll
            for (int j = 0; j < 18; ++j)
                win[ox * 18 + j] = base[ox * 48 + j];

        float h[12];
        #pragma unroll
        for (int n = 0; n < 12; ++n) h[n] = b1[n];
        #pragma unroll
        for (int k = 0; k < 54; ++k) {
            const float wk = win[k];
            #pragma unroll
            for (int n = 0; n < 12; ++n)
                h[n] = fmaf(wk, W1[k * 12 + n], h[n]);   // W1 index wave-uniform -> s_load
        }
        #pragma unroll
        for (int n = 0; n < 12; ++n) h[n] = fminf(fmaxf(h[n], -1.f), 1.f);

        float h2[12];
        #pragma unroll
        for (int n = 0; n < 12; ++n) h2[n] = b2[n];
        #pragma unroll
        for (int k = 0; k < 12; ++k) {
            const float hk = h[k];
            #pragma unroll
            for (int n = 0; n < 12; ++n)
                h2[n] = fmaf(hk, W2[k * 12 + n], h2[n]);
        }
        #pragma unroll
        for (int n = 0; n < 12; ++n) h2[n] = fminf(fmaxf(h2[n], -1.f), 1.f);

        float sg[4];
        #pragma unroll
        for (int n = 0; n < 4; ++n) sg[n] = b3[n];
        #pragma unroll
        for (int k = 0; k < 12; ++k) {
            const float hk = h2[k];
            #pragma unroll
            for (int n = 0; n < 4; ++n)
                sg[n] = fmaf(hk, W3[k * 4 + n], sg[n]);
        }
        #pragma unroll
        for (int n = 0; n < 4; ++n)
            lsight[s * 148 + w * 4 + n] = fminf(fmaxf(sg[n], -1.f), 1.f);
    }
    __syncthreads();

    // ---- phase 2: head 145 -> 32 -> 32 -> 1; 8 threads/sample x 4 channels ----
    {
        const int s  = tid >> 3;
        const int c0 = (tid & 7) * 4;
        const float lastv = inp[(size_t)(s0 + s) * 385 + 384];

        float4 e = *(const float4*)(c1 + c0);
        const float* sgp = lsight + s * 148;
        #pragma unroll 4
        for (int r4 = 0; r4 < 36; ++r4) {
            const float4 sv = *(const float4*)(sgp + r4 * 4);
            const float svv[4] = {sv.x, sv.y, sv.z, sv.w};
            #pragma unroll
            for (int j = 0; j < 4; ++j) {
                const float v = svv[j];
                const float4 wv = *(const float4*)(lv1 + (r4 * 4 + j) * 32 + c0);
                e.x = fmaf(v, wv.x, e.x);
                e.y = fmaf(v, wv.y, e.y);
                e.z = fmaf(v, wv.z, e.z);
                e.w = fmaf(v, wv.w, e.w);
            }
        }
        {
            const float4 wv = *(const float4*)(lv1 + 144 * 32 + c0);
            e.x = fmaf(lastv, wv.x, e.x);
            e.y = fmaf(lastv, wv.y, e.y);
            e.z = fmaf(lastv, wv.z, e.z);
            e.w = fmaf(lastv, wv.w, e.w);
        }
        e.x = fminf(fmaxf(e.x, -1.f), 1.f);
        e.y = fminf(fmaxf(e.y, -1.f), 1.f);
        e.z = fminf(fmaxf(e.z, -1.f), 1.f);
        e.w = fminf(fmaxf(e.w, -1.f), 1.f);

        le1[s * 33 + c0 + 0] = e.x;
        le1[s * 33 + c0 + 1] = e.y;
        le1[s * 33 + c0 + 2] = e.z;
        le1[s * 33 + c0 + 3] = e.w;
        __syncthreads();

        float4 f = *(const float4*)(c2 + c0);
        #pragma unroll
        for (int r = 0; r < 32; ++r) {
            const float v = le1[s * 33 + r];
            const float4 wv = *(const float4*)(lw2 + r * 32 + c0);
            f.x = fmaf(v, wv.x, f.x);
            f.y = fmaf(v, wv.y, f.y);
            f.z = fmaf(v, wv.z, f.z);
            f.w = fmaf(v, wv.w, f.w);
        }
        f.x = fminf(fmaxf(f.x, -1.f), 1.f);
        f.y = fminf(fmaxf(f.y, -1.f), 1.f);
        f.z = fminf(fmaxf(f.z, -1.f), 1.f);
        f.w = fminf(fmaxf(f.w, -1.f), 1.f);

        const float4 v3 = *(const float4*)(V3 + c0);
        float part = f.x * v3.x + f.y * v3.y + f.z * v3.z + f.w * v3.w;
        part += __shfl_xor(part, 1);
        part += __shfl_xor(part, 2);
        part += __shfl_xor(part, 4);
        if ((tid & 7) == 0)
            out[s0 + s] = fminf(fmaxf(part + c3[0], -1.f), 1.f);
    }
}

extern "C" void kernel_launch(void* const* d_in, const int* in_sizes, int n_in,
                              void* d_out, int out_size, void* d_ws, size_t ws_size,
                              hipStream_t stream) {
    const float* inp = (const float*)d_in[0];
    const float* W1  = (const float*)d_in[1];
    const float* b1  = (const float*)d_in[2];
    const float* W2  = (const float*)d_in[3];
    const float* b2  = (const float*)d_in[4];
    const float* W3  = (const float*)d_in[5];
    const float* b3  = (const float*)d_in[6];
    const float* V1  = (const float*)d_in[7];
    const float* c1  = (const float*)d_in[8];
    const float* V2  = (const float*)d_in[9];
    const float* c2  = (const float*)d_in[10];
    const float* V3  = (const float*)d_in[11];
    const float* c3  = (const float*)d_in[12];
    float* out = (float*)d_out;

    const int Btot   = in_sizes[0] / 385;   // 131072
    const int blocks = Btot / SPB;          // 4096

    lila_fused<<<dim3(blocks), dim3(NT), 0, stream>>>(
        inp, W1, b1, W2, b2, W3, b3, V1, c1, V2, c2, V3, c3, out);
}